// Round 2
// baseline (6997.639 us; speedup 1.0000x reference)
//
#include <hip/hip_runtime.h>
#include <hip/hip_bf16.h>
#include <math.h>

#define BB 64
#define TT 256
#define LCH 16
#define DC 50
#define CHN 100
#define DW 300
#define DF 20
#define HID 256
#define G4 1024
#define INDIM 420
#define NTAG 52
#define TSTART 50
#define TSTOP 51

// ------------------- workspace layout (bytes) -------------------
static constexpr size_t OFF_POOL  = 0;                       // 6,553,600
static constexpr size_t OFF_X     = 6553600;                 // 27,525,120 -> end 34,078,720
static constexpr size_t OFF_HF    = 0;                       // 16,777,216 (overlaps pooled+x, dead by then)
static constexpr size_t OFF_HB    = 16777216;                // 16,777,216 -> 33,554,432
static constexpr size_t OFF_XSF   = 34078720;                // 67,108,864
static constexpr size_t OFF_XSB   = 101187584;               // 67,108,864 -> 168,296,448
static constexpr size_t OFF_FEATS = 168296448;               // 3,407,872  -> 171,704,320
static constexpr size_t OFF_WPF   = 171704320;               // 1,048,576
static constexpr size_t OFF_WPB   = 172752896;               // 1,048,576
static constexpr size_t OFF_LOSSB = 173801472;               // 256

__device__ __forceinline__ float sigm(float x) { return 1.0f / (1.0f + expf(-x)); }

// ---- pack W_hh (1024x256 row-major, rows = gate*256+j) into lane-major layout:
//   wp[s][g][kk4][j][q] = W[g*256+j][s*64 + kk4*4 + q]
// flat float index e = (((s*4+g)*16 + kk4)*256 + j)*4 + q
__global__ void k_pack(const float* __restrict__ w, float* __restrict__ wp) {
    int e = blockIdx.x * 256 + threadIdx.x;         // 0..262143
    int s   = e >> 16;
    int r1  = e & 65535;
    int g   = r1 >> 14;
    int r2  = r1 & 16383;
    int kk4 = r2 >> 10;
    int r3  = r2 & 1023;
    int j   = r3 >> 2;
    int q   = r3 & 3;
    wp[e] = w[(g * 256 + j) * HID + (s * 64 + kk4 * 4 + q)];
}

// ---- char CNN: one block (128 thr) per word; conv k=3 pad=1 over L=16, maxpool
__global__ __launch_bounds__(128) void k_charcnn(const int* __restrict__ bchar,
                                                 const float* __restrict__ cemb,
                                                 const float* __restrict__ cw,
                                                 const float* __restrict__ cb,
                                                 float* __restrict__ pooled) {
    __shared__ float ET[DC][20];   // transposed emb with halo cols 0 and 17 = 0
    __shared__ int ids[LCH];
    int w = blockIdx.x;
    int tid = threadIdx.x;
    if (tid < LCH) ids[tid] = bchar[w * LCH + tid];
    __syncthreads();
    for (int s = tid; s < DC * 18; s += 128) {
        int d = s / 18, l = s % 18;
        float v = 0.f;
        if (l >= 1 && l <= 16) v = cemb[ids[l - 1] * DC + d];
        ET[d][l] = v;
    }
    __syncthreads();
    if (tid < CHN) {
        float acc[16];
#pragma unroll
        for (int l = 0; l < 16; l++) acc[l] = 0.f;
        for (int d = 0; d < DC; d++) {
            float e[18];
            float4 t0 = *(const float4*)&ET[d][0];
            float4 t1 = *(const float4*)&ET[d][4];
            float4 t2 = *(const float4*)&ET[d][8];
            float4 t3 = *(const float4*)&ET[d][12];
            e[0]=t0.x; e[1]=t0.y; e[2]=t0.z; e[3]=t0.w;
            e[4]=t1.x; e[5]=t1.y; e[6]=t1.z; e[7]=t1.w;
            e[8]=t2.x; e[9]=t2.y; e[10]=t2.z; e[11]=t2.w;
            e[12]=t3.x; e[13]=t3.y; e[14]=t3.z; e[15]=t3.w;
            e[16]=ET[d][16]; e[17]=ET[d][17];
            float w0 = cw[(tid * DC + d) * 3 + 0];
            float w1 = cw[(tid * DC + d) * 3 + 1];
            float w2 = cw[(tid * DC + d) * 3 + 2];
#pragma unroll
            for (int l = 0; l < 16; l++)
                acc[l] += w0 * e[l] + w1 * e[l + 1] + w2 * e[l + 2];
        }
        float m = acc[0];
#pragma unroll
        for (int l = 1; l < 16; l++) m = fmaxf(m, acc[l]);
        pooled[w * CHN + tid] = m + cb[tid];
    }
}

// ---- assemble x[16384][420] = [word_emb | char_feats(recovered) | feat_emb]
__global__ __launch_bounds__(128) void k_concat(const int* __restrict__ word,
                                                const int* __restrict__ featsidx,
                                                const int* __restrict__ recover,
                                                const float* __restrict__ wemb,
                                                const float* __restrict__ femb,
                                                const float* __restrict__ pooled,
                                                float* __restrict__ x) {
    int w = blockIdx.x;
    int tid = threadIdx.x;
    int b = w >> 8;
    int wid = word[w];
    for (int c = tid; c < DW; c += 128) x[(size_t)w * INDIM + c] = wemb[(size_t)wid * DW + c];
    int rc = recover[w];
    if (tid < CHN) x[(size_t)w * INDIM + DW + tid] = pooled[rc * CHN + tid];
    if (tid < DF)  x[(size_t)w * INDIM + DW + CHN + tid] = femb[featsidx[b] * DF + tid];
}

// ---- fp32 GEMM: C[m][g] = sum_k A[m][k]*W[g][k] + bias[g];  M=16384 N=1024 K=420
#define BM 128
#define BN 64
#define BK 16
__global__ __launch_bounds__(256) void k_gemm(const float* __restrict__ A,
                                              const float* __restrict__ Wt,
                                              const float* __restrict__ bias,
                                              float* __restrict__ C) {
    __shared__ float As[BK][BM];
    __shared__ float Bs[BK][BN];
    int tid = threadIdx.x;
    int tx = tid & 15, ty = tid >> 4;
    int m0 = blockIdx.y * BM, n0 = blockIdx.x * BN;
    float acc[8][4];
#pragma unroll
    for (int i = 0; i < 8; i++)
#pragma unroll
        for (int jj = 0; jj < 4; jj++) acc[i][jj] = 0.f;
    int am = tid >> 1, ak = (tid & 1) * 8;
    int bn = tid >> 2, bk = (tid & 3) * 4;
    for (int k0 = 0; k0 < INDIM; k0 += BK) {
#pragma unroll
        for (int q = 0; q < 8; q++) {
            int k = k0 + ak + q;
            As[ak + q][am] = (k < INDIM) ? A[(size_t)(m0 + am) * INDIM + k] : 0.f;
        }
#pragma unroll
        for (int q = 0; q < 4; q++) {
            int k = k0 + bk + q;
            Bs[bk + q][bn] = (k < INDIM) ? Wt[(size_t)(n0 + bn) * INDIM + k] : 0.f;
        }
        __syncthreads();
#pragma unroll
        for (int kk = 0; kk < BK; kk++) {
            float4 a0 = *(const float4*)&As[kk][ty * 8];
            float4 a1 = *(const float4*)&As[kk][ty * 8 + 4];
            float4 b0 = *(const float4*)&Bs[kk][tx * 4];
            float ra[8] = {a0.x, a0.y, a0.z, a0.w, a1.x, a1.y, a1.z, a1.w};
            float rb[4] = {b0.x, b0.y, b0.z, b0.w};
#pragma unroll
            for (int i = 0; i < 8; i++)
#pragma unroll
                for (int jj = 0; jj < 4; jj++) acc[i][jj] += ra[i] * rb[jj];
        }
        __syncthreads();
    }
    float4 bv = *(const float4*)&bias[n0 + tx * 4];
#pragma unroll
    for (int i = 0; i < 8; i++) {
        float4 o;
        o.x = acc[i][0] + bv.x; o.y = acc[i][1] + bv.y;
        o.z = acc[i][2] + bv.z; o.w = acc[i][3] + bv.w;
        *(float4*)&C[(size_t)(m0 + ty * 8 + i) * G4 + n0 + tx * 4] = o;
    }
}

// ---- masked BiLSTM: one 1024-thread block per (batch, dir).
// thread (j = tid&255, s = tid>>8) computes 4 gate partials for unit j over
// k in [64s, 64s+64) using lane-major packed weights; epilogue by threads 0-255.
__global__ __launch_bounds__(1024) void k_lstm(const float* __restrict__ xs_f,
                                               const float* __restrict__ xs_b,
                                               const float* __restrict__ wp_f,
                                               const float* __restrict__ wp_b,
                                               const int* __restrict__ wlen,
                                               float* __restrict__ h_f,
                                               float* __restrict__ h_b) {
    int b = blockIdx.x & 63, d = blockIdx.x >> 6;
    const float* xs = d ? xs_b : xs_f;
    const float4* wp4 = (const float4*)(d ? wp_b : wp_f);
    float* ho = d ? h_b : h_f;
    int len = wlen[b];
    __shared__ float __align__(16) hsh[HID];
    __shared__ float __align__(16) part[4][4][HID];   // [gate][ksec][unit]
    int tid = threadIdx.x;
    int j = tid & 255, s = tid >> 8;
    if (tid < HID) hsh[tid] = 0.f;
    float c = 0.f;
    // per-thread weight bases (float4 units): wp4[(s*4+g)*4096 + kk4*256 + j]
    const float4* w0b = wp4 + (size_t)(s * 4 + 0) * 4096 + j;
    const float4* w1b = wp4 + (size_t)(s * 4 + 1) * 4096 + j;
    const float4* w2b = wp4 + (size_t)(s * 4 + 2) * 4096 + j;
    const float4* w3b = wp4 + (size_t)(s * 4 + 3) * 4096 + j;
    __syncthreads();
    for (int ss = 0; ss < len; ss++) {
        int t = d ? (len - 1 - ss) : ss;
        const float* xr = xs + (size_t)(b * TT + t) * G4;
        float xv = xr[s * 256 + j];                   // folded input projection
        float acc0 = (s == 0) ? xv : 0.f;
        float acc1 = (s == 1) ? xv : 0.f;
        float acc2 = (s == 2) ? xv : 0.f;
        float acc3 = (s == 3) ? xv : 0.f;
#pragma unroll
        for (int kk4 = 0; kk4 < 16; kk4++) {
            float4 h4 = *(const float4*)&hsh[s * 64 + kk4 * 4];
            float4 wa = w0b[kk4 * 256];
            float4 wb = w1b[kk4 * 256];
            float4 wc = w2b[kk4 * 256];
            float4 wd = w3b[kk4 * 256];
            acc0 += wa.x * h4.x + wa.y * h4.y + wa.z * h4.z + wa.w * h4.w;
            acc1 += wb.x * h4.x + wb.y * h4.y + wb.z * h4.z + wb.w * h4.w;
            acc2 += wc.x * h4.x + wc.y * h4.y + wc.z * h4.z + wc.w * h4.w;
            acc3 += wd.x * h4.x + wd.y * h4.y + wd.z * h4.z + wd.w * h4.w;
        }
        part[0][s][j] = acc0;
        part[1][s][j] = acc1;
        part[2][s][j] = acc2;
        part[3][s][j] = acc3;
        __syncthreads();
        if (tid < HID) {
            float g0 = part[0][0][tid] + part[0][1][tid] + part[0][2][tid] + part[0][3][tid];
            float g1 = part[1][0][tid] + part[1][1][tid] + part[1][2][tid] + part[1][3][tid];
            float g2 = part[2][0][tid] + part[2][1][tid] + part[2][2][tid] + part[2][3][tid];
            float g3 = part[3][0][tid] + part[3][1][tid] + part[3][2][tid] + part[3][3][tid];
            float ig = sigm(g0), fg = sigm(g1), gg = tanhf(g2), og = sigm(g3);
            c = fg * c + ig * gg;
            float h = og * tanhf(c);
            hsh[tid] = h;
            ho[(size_t)(b * TT + t) * HID + tid] = h;
        }
        __syncthreads();
    }
}

// ---- projection: feats[w][52] = [hf|hb] . proj_w[j] + proj_b[j]
__global__ __launch_bounds__(64) void k_proj(const float* __restrict__ hf,
                                             const float* __restrict__ hb,
                                             const float* __restrict__ pw,
                                             const float* __restrict__ pb,
                                             float* __restrict__ feats) {
    __shared__ float hc[512];
    int w = blockIdx.x;
    int tid = threadIdx.x;
    {
        float4 v = *(const float4*)&hf[(size_t)w * HID + tid * 4];
        *(float4*)&hc[tid * 4] = v;
        float4 u = *(const float4*)&hb[(size_t)w * HID + tid * 4];
        *(float4*)&hc[256 + tid * 4] = u;
    }
    __syncthreads();
    if (tid < NTAG) {
        float s = pb[tid];
        for (int k = 0; k < 512; k += 4) {
            float4 h4 = *(const float4*)&hc[k];
            float4 w4 = *(const float4*)&pw[(size_t)tid * 512 + k];
            s += h4.x * w4.x + h4.y * w4.y + h4.z * w4.z + h4.w * w4.w;
        }
        feats[(size_t)w * NTAG + tid] = s;
    }
}

// ---- CRF: forward (Z), gold score, viterbi + backtrace. one block per batch
__global__ __launch_bounds__(64) void k_crf(const float* __restrict__ feats,
                                            const float* __restrict__ trans,
                                            const int* __restrict__ wlen,
                                            const int* __restrict__ blabel,
                                            float* __restrict__ lossb,
                                            float* __restrict__ outtags) {
    __shared__ float Tm[NTAG * NTAG];
    __shared__ float alpha[NTAG], valpha[NTAG], frow[NTAG], red[NTAG];
    __shared__ unsigned char bp[TT - 1][NTAG];
    int b = blockIdx.x;
    int j = threadIdx.x;
    for (int s = j; s < NTAG * NTAG; s += 64) Tm[s] = trans[s];
    __syncthreads();
    int len = wlen[b];
    const float* fb = feats + (size_t)b * TT * NTAG;
    if (j < NTAG) {
        float a = fb[j] + Tm[TSTART * NTAG + j];
        alpha[j] = a;
        valpha[j] = a;
    }
    __syncthreads();
    for (int t = 1; t < len; t++) {
        if (j < NTAG) frow[j] = fb[(size_t)t * NTAG + j];
        __syncthreads();
        float anew = 0.f, vnew = 0.f;
        int arg = 0;
        if (j < NTAG) {
            float m1 = -1e30f;
            for (int i = 0; i < NTAG; i++) m1 = fmaxf(m1, alpha[i] + Tm[i * NTAG + j]);
            float ssum = 0.f;
            for (int i = 0; i < NTAG; i++) ssum += expf(alpha[i] + Tm[i * NTAG + j] - m1);
            anew = m1 + logf(ssum) + frow[j];
            float vm = -1e30f;
            for (int i = 0; i < NTAG; i++) {
                float sv = valpha[i] + Tm[i * NTAG + j];
                if (sv > vm) { vm = sv; arg = i; }   // strict > keeps first max (jnp.argmax)
            }
            vnew = vm + frow[j];
        }
        __syncthreads();
        if (j < NTAG) {
            alpha[j] = anew;
            valpha[j] = vnew;
            bp[t - 1][j] = (unsigned char)arg;
        }
        __syncthreads();
    }
    // ---- Z + gold (thread 0) ----
    if (j < NTAG) red[j] = alpha[j] + Tm[j * NTAG + TSTOP];
    __syncthreads();
    float Zg = 0.f, goldv = 0.f;
    if (j == 0) {
        float m1 = red[0];
        for (int i = 1; i < NTAG; i++) m1 = fmaxf(m1, red[i]);
        float ssum = 0.f;
        for (int i = 0; i < NTAG; i++) ssum += expf(red[i] - m1);
        Zg = m1 + logf(ssum);
        const int* lab = blabel + b * TT;
        goldv = Tm[TSTART * NTAG + lab[0]] + fb[lab[0]];
        for (int t = 1; t < len; t++)
            goldv += Tm[lab[t - 1] * NTAG + lab[t]] + fb[(size_t)t * NTAG + lab[t]];
        goldv += Tm[lab[len - 1] * NTAG + TSTOP];
    }
    __syncthreads();
    // ---- viterbi terminal + backtrace ----
    if (j < NTAG) red[j] = valpha[j] + Tm[j * NTAG + TSTOP];
    __syncthreads();
    if (j == 0) {
        int best = 0;
        float vm = red[0];
        for (int i = 1; i < NTAG; i++)
            if (red[i] > vm) { vm = red[i]; best = i; }
        float* ot = outtags + (size_t)b * TT;
        int tag = best;
        ot[len - 1] = (float)tag;
        for (int t = len - 2; t >= 0; t--) {
            tag = bp[t][tag];
            ot[t] = (float)tag;
        }
        for (int t = len; t < TT; t++) ot[t] = 0.f;
        lossb[b] = Zg - goldv;
    }
}

// ---- deterministic final loss reduction
__global__ void k_loss(const float* __restrict__ lossb, float* __restrict__ out) {
    if (threadIdx.x == 0 && blockIdx.x == 0) {
        float s = 0.f;
        for (int i = 0; i < BB; i++) s += lossb[i];
        out[0] = s;
    }
}

extern "C" void kernel_launch(void* const* d_in, const int* in_sizes, int n_in,
                              void* d_out, int out_size, void* d_ws, size_t ws_size,
                              hipStream_t stream) {
    const int* batch_word     = (const int*)d_in[0];
    const int* batch_features = (const int*)d_in[1];
    const int* batch_wordlen  = (const int*)d_in[2];
    const int* batch_char     = (const int*)d_in[3];
    const int* batch_recover  = (const int*)d_in[5];
    const int* batch_label    = (const int*)d_in[7];
    const float* char_emb = (const float*)d_in[8];
    const float* conv_w   = (const float*)d_in[9];
    const float* conv_b   = (const float*)d_in[10];
    const float* word_emb = (const float*)d_in[11];
    const float* feat_emb = (const float*)d_in[12];
    const float* w_ih_f   = (const float*)d_in[13];
    const float* w_hh_f   = (const float*)d_in[14];
    const float* b_f      = (const float*)d_in[15];
    const float* w_ih_b   = (const float*)d_in[16];
    const float* w_hh_b   = (const float*)d_in[17];
    const float* b_b      = (const float*)d_in[18];
    const float* proj_w   = (const float*)d_in[19];
    const float* proj_b   = (const float*)d_in[20];
    const float* trans    = (const float*)d_in[21];

    char* ws = (char*)d_ws;
    float* pooled = (float*)(ws + OFF_POOL);
    float* x      = (float*)(ws + OFF_X);
    float* h_f    = (float*)(ws + OFF_HF);
    float* h_b    = (float*)(ws + OFF_HB);
    float* xs_f   = (float*)(ws + OFF_XSF);
    float* xs_b   = (float*)(ws + OFF_XSB);
    float* feats  = (float*)(ws + OFF_FEATS);
    float* wp_f   = (float*)(ws + OFF_WPF);
    float* wp_b   = (float*)(ws + OFF_WPB);
    float* lossb  = (float*)(ws + OFF_LOSSB);

    k_pack<<<1024, 256, 0, stream>>>(w_hh_f, wp_f);
    k_pack<<<1024, 256, 0, stream>>>(w_hh_b, wp_b);
    k_charcnn<<<BB * TT, 128, 0, stream>>>(batch_char, char_emb, conv_w, conv_b, pooled);
    k_concat<<<BB * TT, 128, 0, stream>>>(batch_word, batch_features, batch_recover,
                                          word_emb, feat_emb, pooled, x);
    k_gemm<<<dim3(G4 / BN, (BB * TT) / BM), 256, 0, stream>>>(x, w_ih_f, b_f, xs_f);
    k_gemm<<<dim3(G4 / BN, (BB * TT) / BM), 256, 0, stream>>>(x, w_ih_b, b_b, xs_b);
    k_lstm<<<128, 1024, 0, stream>>>(xs_f, xs_b, wp_f, wp_b, batch_wordlen, h_f, h_b);
    k_proj<<<BB * TT, 64, 0, stream>>>(h_f, h_b, proj_w, proj_b, feats);
    k_crf<<<BB, 64, 0, stream>>>(feats, trans, batch_wordlen, batch_label,
                                 lossb, (float*)d_out + 1);
    k_loss<<<1, 64, 0, stream>>>(lossb, (float*)d_out);
}

// Round 4
// 4075.914 us; speedup vs baseline: 1.7168x; 1.7168x over previous
//
#include <hip/hip_runtime.h>
#include <hip/hip_bf16.h>
#include <math.h>

#define BB 64
#define TT 256
#define LCH 16
#define DC 50
#define CHN 100
#define DW 300
#define DF 20
#define HID 256
#define G4 1024
#define INDIM 420
#define NTAG 52
#define TSTART 50
#define TSTOP 51

// ------------------- workspace layout (bytes) -------------------
static constexpr size_t OFF_POOL  = 0;                       // 6,553,600
static constexpr size_t OFF_X     = 6553600;                 // 27,525,120 -> end 34,078,720
static constexpr size_t OFF_HF    = 0;                       // 16,777,216 (overlaps pooled+x, dead by then)
static constexpr size_t OFF_HB    = 16777216;                // 16,777,216 -> 33,554,432
static constexpr size_t OFF_XSF   = 34078720;                // 67,108,864
static constexpr size_t OFF_XSB   = 101187584;               // 67,108,864 -> 168,296,448
static constexpr size_t OFF_FEATS = 168296448;               // 3,407,872  -> 171,704,320
static constexpr size_t OFF_WPF   = 171704320;               // 512 KB used (fp16, 262144 elems)
static constexpr size_t OFF_WPB   = 172752896;               // 512 KB used (fp16, 262144 elems)
static constexpr size_t OFF_LOSSB = 173801472;               // 256

typedef _Float16 v2h __attribute__((ext_vector_type(2)));
union UH2 { unsigned u; v2h h; };
__device__ __forceinline__ float fdot2u(unsigned a, unsigned b, float c) {
    UH2 x, y; x.u = a; y.u = b;
    return __builtin_amdgcn_fdot2(x.h, y.h, c, false);
}

__device__ __forceinline__ float sigm(float x) { return 1.0f / (1.0f + expf(-x)); }

// ---- pack W_hh (1024x256 f32, rows = gate*256+j) into fp16 lane-major layout:
//   wph[(((s*4+g)*8 + k8)*256 + j)*8 + r] = (f16) W[g*256+j][s*64 + k8*8 + r]
// total elements = 4*4*8*256*8 = 262144  (s in 0..3!)
__global__ void k_packh(const float* __restrict__ w, _Float16* __restrict__ wph) {
    int e = blockIdx.x * 256 + threadIdx.x;     // 0..262143 (grid must be 1024 blocks)
    if (e >= 262144) return;
    int r  = e & 7;
    int j  = (e >> 3) & 255;
    int k8 = (e >> 11) & 7;
    int g  = (e >> 14) & 3;
    int s  = (e >> 16) & 3;
    wph[e] = (_Float16)w[(g * 256 + j) * HID + (s * 64 + k8 * 8 + r)];
}

// ---- char CNN: one block (128 thr) per word; conv k=3 pad=1 over L=16, maxpool
__global__ __launch_bounds__(128) void k_charcnn(const int* __restrict__ bchar,
                                                 const float* __restrict__ cemb,
                                                 const float* __restrict__ cw,
                                                 const float* __restrict__ cb,
                                                 float* __restrict__ pooled) {
    __shared__ float ET[DC][20];   // transposed emb with halo cols 0 and 17 = 0
    __shared__ int ids[LCH];
    int w = blockIdx.x;
    int tid = threadIdx.x;
    if (tid < LCH) ids[tid] = bchar[w * LCH + tid];
    __syncthreads();
    for (int s = tid; s < DC * 18; s += 128) {
        int d = s / 18, l = s % 18;
        float v = 0.f;
        if (l >= 1 && l <= 16) v = cemb[ids[l - 1] * DC + d];
        ET[d][l] = v;
    }
    __syncthreads();
    if (tid < CHN) {
        float acc[16];
#pragma unroll
        for (int l = 0; l < 16; l++) acc[l] = 0.f;
        for (int d = 0; d < DC; d++) {
            float e[18];
            float4 t0 = *(const float4*)&ET[d][0];
            float4 t1 = *(const float4*)&ET[d][4];
            float4 t2 = *(const float4*)&ET[d][8];
            float4 t3 = *(const float4*)&ET[d][12];
            e[0]=t0.x; e[1]=t0.y; e[2]=t0.z; e[3]=t0.w;
            e[4]=t1.x; e[5]=t1.y; e[6]=t1.z; e[7]=t1.w;
            e[8]=t2.x; e[9]=t2.y; e[10]=t2.z; e[11]=t2.w;
            e[12]=t3.x; e[13]=t3.y; e[14]=t3.z; e[15]=t3.w;
            e[16]=ET[d][16]; e[17]=ET[d][17];
            float w0 = cw[(tid * DC + d) * 3 + 0];
            float w1 = cw[(tid * DC + d) * 3 + 1];
            float w2 = cw[(tid * DC + d) * 3 + 2];
#pragma unroll
            for (int l = 0; l < 16; l++)
                acc[l] += w0 * e[l] + w1 * e[l + 1] + w2 * e[l + 2];
        }
        float m = acc[0];
#pragma unroll
        for (int l = 1; l < 16; l++) m = fmaxf(m, acc[l]);
        pooled[w * CHN + tid] = m + cb[tid];
    }
}

// ---- assemble x[16384][420] = [word_emb | char_feats(recovered) | feat_emb]
__global__ __launch_bounds__(128) void k_concat(const int* __restrict__ word,
                                                const int* __restrict__ featsidx,
                                                const int* __restrict__ recover,
                                                const float* __restrict__ wemb,
                                                const float* __restrict__ femb,
                                                const float* __restrict__ pooled,
                                                float* __restrict__ x) {
    int w = blockIdx.x;
    int tid = threadIdx.x;
    int b = w >> 8;
    int wid = word[w];
    for (int c = tid; c < DW; c += 128) x[(size_t)w * INDIM + c] = wemb[(size_t)wid * DW + c];
    int rc = recover[w];
    if (tid < CHN) x[(size_t)w * INDIM + DW + tid] = pooled[rc * CHN + tid];
    if (tid < DF)  x[(size_t)w * INDIM + DW + CHN + tid] = femb[featsidx[b] * DF + tid];
}

// ---- fp32 GEMM: C[m][g] = sum_k A[m][k]*W[g][k] + bias[g];  M=16384 N=1024 K=420
#define BM 128
#define BN 64
#define BK 16
__global__ __launch_bounds__(256) void k_gemm(const float* __restrict__ A,
                                              const float* __restrict__ Wt,
                                              const float* __restrict__ bias,
                                              float* __restrict__ C) {
    __shared__ float As[BK][BM];
    __shared__ float Bs[BK][BN];
    int tid = threadIdx.x;
    int tx = tid & 15, ty = tid >> 4;
    int m0 = blockIdx.y * BM, n0 = blockIdx.x * BN;
    float acc[8][4];
#pragma unroll
    for (int i = 0; i < 8; i++)
#pragma unroll
        for (int jj = 0; jj < 4; jj++) acc[i][jj] = 0.f;
    int am = tid >> 1, ak = (tid & 1) * 8;
    int bn = tid >> 2, bk = (tid & 3) * 4;
    for (int k0 = 0; k0 < INDIM; k0 += BK) {
#pragma unroll
        for (int q = 0; q < 8; q++) {
            int k = k0 + ak + q;
            As[ak + q][am] = (k < INDIM) ? A[(size_t)(m0 + am) * INDIM + k] : 0.f;
        }
#pragma unroll
        for (int q = 0; q < 4; q++) {
            int k = k0 + bk + q;
            Bs[bk + q][bn] = (k < INDIM) ? Wt[(size_t)(n0 + bn) * INDIM + k] : 0.f;
        }
        __syncthreads();
#pragma unroll
        for (int kk = 0; kk < BK; kk++) {
            float4 a0 = *(const float4*)&As[kk][ty * 8];
            float4 a1 = *(const float4*)&As[kk][ty * 8 + 4];
            float4 b0 = *(const float4*)&Bs[kk][tx * 4];
            float ra[8] = {a0.x, a0.y, a0.z, a0.w, a1.x, a1.y, a1.z, a1.w};
            float rb[4] = {b0.x, b0.y, b0.z, b0.w};
#pragma unroll
            for (int i = 0; i < 8; i++)
#pragma unroll
                for (int jj = 0; jj < 4; jj++) acc[i][jj] += ra[i] * rb[jj];
        }
        __syncthreads();
    }
    float4 bv = *(const float4*)&bias[n0 + tx * 4];
#pragma unroll
    for (int i = 0; i < 8; i++) {
        float4 o;
        o.x = acc[i][0] + bv.x; o.y = acc[i][1] + bv.y;
        o.z = acc[i][2] + bv.z; o.w = acc[i][3] + bv.w;
        *(float4*)&C[(size_t)(m0 + ty * 8 + i) * G4 + n0 + tx * 4] = o;
    }
}

// ---- masked BiLSTM: one 1024-thread block per (batch PAIR, dir); 64 blocks.
// Weights fp16 (lane-major), fp32 accumulate via v_dot2_f32_f16. h state kept
// as packed f16x2 in LDS; c and global h outputs stay fp32.
// thread (j = tid&255, s = tid>>8) computes 4-gate x 2-batch partials over
// k in [64s, 64s+64); epilogue threads (tid<256) each own 2 adjacent units.
__global__ __launch_bounds__(1024) void k_lstm(const float* __restrict__ xs_f,
                                               const float* __restrict__ xs_b,
                                               const _Float16* __restrict__ wh_f,
                                               const _Float16* __restrict__ wh_b,
                                               const int* __restrict__ wlen,
                                               float* __restrict__ h_f,
                                               float* __restrict__ h_b) {
    int d = blockIdx.x >> 5;          // 0 fwd, 1 bwd
    int p = blockIdx.x & 31;          // batch pair
    int bb = p * 2;
    const float* xs = d ? xs_b : xs_f;
    const uint4* wp4 = (const uint4*)(d ? wh_b : wh_f);
    float* ho = d ? h_b : h_f;
    int len0 = wlen[bb], len1 = wlen[bb + 1];
    int lenmax = max(len0, len1);
    __shared__ unsigned __align__(16) hh[2][128];      // f16x2-packed h state
    __shared__ float part[4][4][2][256];               // [s][gate][bat][unit]
    int tid = threadIdx.x;
    int j = tid & 255, s = tid >> 8;
    if (tid < 256) ((unsigned*)hh)[tid] = 0u;
    float c0 = 0.f, c1 = 0.f;                          // epilogue cell states (2 units)
    // per-thread weight bases (uint4 = 8 fp16): idx (((s*4+g)*8 + k8)*256 + j)
    const uint4* wq0 = wp4 + (size_t)((s * 4 + 0) * 8) * 256 + j;
    const uint4* wq1 = wp4 + (size_t)((s * 4 + 1) * 8) * 256 + j;
    const uint4* wq2 = wp4 + (size_t)((s * 4 + 2) * 8) * 256 + j;
    const uint4* wq3 = wp4 + (size_t)((s * 4 + 3) * 8) * 256 + j;
    const uint4* hp0 = (const uint4*)&hh[0][0];
    const uint4* hp1 = (const uint4*)&hh[1][0];
    __syncthreads();
    for (int ss = 0; ss < lenmax; ++ss) {
        float a00 = 0.f, a01 = 0.f, a10 = 0.f, a11 = 0.f;
        float a20 = 0.f, a21 = 0.f, a30 = 0.f, a31 = 0.f;
#pragma unroll
        for (int k8 = 0; k8 < 8; k8++) {
            uint4 ha = hp0[s * 8 + k8];
            uint4 hb = hp1[s * 8 + k8];
            uint4 w0 = wq0[k8 * 256];
            uint4 w1 = wq1[k8 * 256];
            uint4 w2 = wq2[k8 * 256];
            uint4 w3 = wq3[k8 * 256];
            a00 = fdot2u(w0.x, ha.x, a00); a00 = fdot2u(w0.y, ha.y, a00);
            a00 = fdot2u(w0.z, ha.z, a00); a00 = fdot2u(w0.w, ha.w, a00);
            a01 = fdot2u(w0.x, hb.x, a01); a01 = fdot2u(w0.y, hb.y, a01);
            a01 = fdot2u(w0.z, hb.z, a01); a01 = fdot2u(w0.w, hb.w, a01);
            a10 = fdot2u(w1.x, ha.x, a10); a10 = fdot2u(w1.y, ha.y, a10);
            a10 = fdot2u(w1.z, ha.z, a10); a10 = fdot2u(w1.w, ha.w, a10);
            a11 = fdot2u(w1.x, hb.x, a11); a11 = fdot2u(w1.y, hb.y, a11);
            a11 = fdot2u(w1.z, hb.z, a11); a11 = fdot2u(w1.w, hb.w, a11);
            a20 = fdot2u(w2.x, ha.x, a20); a20 = fdot2u(w2.y, ha.y, a20);
            a20 = fdot2u(w2.z, ha.z, a20); a20 = fdot2u(w2.w, ha.w, a20);
            a21 = fdot2u(w2.x, hb.x, a21); a21 = fdot2u(w2.y, hb.y, a21);
            a21 = fdot2u(w2.z, hb.z, a21); a21 = fdot2u(w2.w, hb.w, a21);
            a30 = fdot2u(w3.x, ha.x, a30); a30 = fdot2u(w3.y, ha.y, a30);
            a30 = fdot2u(w3.z, ha.z, a30); a30 = fdot2u(w3.w, ha.w, a30);
            a31 = fdot2u(w3.x, hb.x, a31); a31 = fdot2u(w3.y, hb.y, a31);
            a31 = fdot2u(w3.z, hb.z, a31); a31 = fdot2u(w3.w, hb.w, a31);
        }
        part[s][0][0][j] = a00; part[s][0][1][j] = a01;
        part[s][1][0][j] = a10; part[s][1][1][j] = a11;
        part[s][2][0][j] = a20; part[s][2][1][j] = a21;
        part[s][3][0][j] = a30; part[s][3][1][j] = a31;
        __syncthreads();
        if (tid < 256) {
            int bat = tid >> 7, j2 = tid & 127;
            int len = bat ? len1 : len0;
            if (ss < len) {
                int t = d ? (len - 1 - ss) : ss;
                const float2* xr2 = (const float2*)(xs + (size_t)((bb + bat) * TT + t) * G4);
                float sum[4][2];
#pragma unroll
                for (int g = 0; g < 4; g++) {
                    float2 xv = xr2[g * 128 + j2];
                    sum[g][0] = part[0][g][bat][2 * j2] + part[1][g][bat][2 * j2]
                              + part[2][g][bat][2 * j2] + part[3][g][bat][2 * j2] + xv.x;
                    sum[g][1] = part[0][g][bat][2 * j2 + 1] + part[1][g][bat][2 * j2 + 1]
                              + part[2][g][bat][2 * j2 + 1] + part[3][g][bat][2 * j2 + 1] + xv.y;
                }
                float i0 = sigm(sum[0][0]), f0 = sigm(sum[1][0]);
                float z0 = tanhf(sum[2][0]), o0 = sigm(sum[3][0]);
                c0 = f0 * c0 + i0 * z0;
                float hA = o0 * tanhf(c0);
                float i1 = sigm(sum[0][1]), f1 = sigm(sum[1][1]);
                float z1 = tanhf(sum[2][1]), o1 = sigm(sum[3][1]);
                c1 = f1 * c1 + i1 * z1;
                float hB = o1 * tanhf(c1);
                UH2 pk;
                pk.h[0] = (_Float16)hA;
                pk.h[1] = (_Float16)hB;
                hh[bat][j2] = pk.u;
                float2 st; st.x = hA; st.y = hB;
                *(float2*)&ho[(size_t)((bb + bat) * TT + t) * HID + 2 * j2] = st;
            }
        }
        __syncthreads();
    }
}

// ---- projection: feats[w][52] = [hf|hb] . proj_w[j] + proj_b[j]
__global__ __launch_bounds__(64) void k_proj(const float* __restrict__ hf,
                                             const float* __restrict__ hb,
                                             const float* __restrict__ pw,
                                             const float* __restrict__ pb,
                                             float* __restrict__ feats) {
    __shared__ float hc[512];
    int w = blockIdx.x;
    int tid = threadIdx.x;
    {
        float4 v = *(const float4*)&hf[(size_t)w * HID + tid * 4];
        *(float4*)&hc[tid * 4] = v;
        float4 u = *(const float4*)&hb[(size_t)w * HID + tid * 4];
        *(float4*)&hc[256 + tid * 4] = u;
    }
    __syncthreads();
    if (tid < NTAG) {
        float s = pb[tid];
        for (int k = 0; k < 512; k += 4) {
            float4 h4 = *(const float4*)&hc[k];
            float4 w4 = *(const float4*)&pw[(size_t)tid * 512 + k];
            s += h4.x * w4.x + h4.y * w4.y + h4.z * w4.z + h4.w * w4.w;
        }
        feats[(size_t)w * NTAG + tid] = s;
    }
}

// ---- CRF: forward (Z), gold score, viterbi + backtrace. one block per batch
__global__ __launch_bounds__(64) void k_crf(const float* __restrict__ feats,
                                            const float* __restrict__ trans,
                                            const int* __restrict__ wlen,
                                            const int* __restrict__ blabel,
                                            float* __restrict__ lossb,
                                            float* __restrict__ outtags) {
    __shared__ float Tm[NTAG * NTAG];
    __shared__ float alpha[NTAG], valpha[NTAG], frow[NTAG], red[NTAG];
    __shared__ unsigned char bp[TT - 1][NTAG];
    int b = blockIdx.x;
    int j = threadIdx.x;
    for (int s = j; s < NTAG * NTAG; s += 64) Tm[s] = trans[s];
    __syncthreads();
    int len = wlen[b];
    const float* fb = feats + (size_t)b * TT * NTAG;
    if (j < NTAG) {
        float a = fb[j] + Tm[TSTART * NTAG + j];
        alpha[j] = a;
        valpha[j] = a;
    }
    __syncthreads();
    for (int t = 1; t < len; t++) {
        if (j < NTAG) frow[j] = fb[(size_t)t * NTAG + j];
        __syncthreads();
        float anew = 0.f, vnew = 0.f;
        int arg = 0;
        if (j < NTAG) {
            float m1 = -1e30f;
            for (int i = 0; i < NTAG; i++) m1 = fmaxf(m1, alpha[i] + Tm[i * NTAG + j]);
            float ssum = 0.f;
            for (int i = 0; i < NTAG; i++) ssum += expf(alpha[i] + Tm[i * NTAG + j] - m1);
            anew = m1 + logf(ssum) + frow[j];
            float vm = -1e30f;
            for (int i = 0; i < NTAG; i++) {
                float sv = valpha[i] + Tm[i * NTAG + j];
                if (sv > vm) { vm = sv; arg = i; }   // strict > keeps first max (jnp.argmax)
            }
            vnew = vm + frow[j];
        }
        __syncthreads();
        if (j < NTAG) {
            alpha[j] = anew;
            valpha[j] = vnew;
            bp[t - 1][j] = (unsigned char)arg;
        }
        __syncthreads();
    }
    // ---- Z + gold (thread 0) ----
    if (j < NTAG) red[j] = alpha[j] + Tm[j * NTAG + TSTOP];
    __syncthreads();
    float Zg = 0.f, goldv = 0.f;
    if (j == 0) {
        float m1 = red[0];
        for (int i = 1; i < NTAG; i++) m1 = fmaxf(m1, red[i]);
        float ssum = 0.f;
        for (int i = 0; i < NTAG; i++) ssum += expf(red[i] - m1);
        Zg = m1 + logf(ssum);
        const int* lab = blabel + b * TT;
        goldv = Tm[TSTART * NTAG + lab[0]] + fb[lab[0]];
        for (int t = 1; t < len; t++)
            goldv += Tm[lab[t - 1] * NTAG + lab[t]] + fb[(size_t)t * NTAG + lab[t]];
        goldv += Tm[lab[len - 1] * NTAG + TSTOP];
    }
    __syncthreads();
    // ---- viterbi terminal + backtrace ----
    if (j < NTAG) red[j] = valpha[j] + Tm[j * NTAG + TSTOP];
    __syncthreads();
    if (j == 0) {
        int best = 0;
        float vm = red[0];
        for (int i = 1; i < NTAG; i++)
            if (red[i] > vm) { vm = red[i]; best = i; }
        float* ot = outtags + (size_t)b * TT;
        int tag = best;
        ot[len - 1] = (float)tag;
        for (int t = len - 2; t >= 0; t--) {
            tag = bp[t][tag];
            ot[t] = (float)tag;
        }
        for (int t = len; t < TT; t++) ot[t] = 0.f;
        lossb[b] = Zg - goldv;
    }
}

// ---- deterministic final loss reduction
__global__ void k_loss(const float* __restrict__ lossb, float* __restrict__ out) {
    if (threadIdx.x == 0 && blockIdx.x == 0) {
        float s = 0.f;
        for (int i = 0; i < BB; i++) s += lossb[i];
        out[0] = s;
    }
}

extern "C" void kernel_launch(void* const* d_in, const int* in_sizes, int n_in,
                              void* d_out, int out_size, void* d_ws, size_t ws_size,
                              hipStream_t stream) {
    const int* batch_word     = (const int*)d_in[0];
    const int* batch_features = (const int*)d_in[1];
    const int* batch_wordlen  = (const int*)d_in[2];
    const int* batch_char     = (const int*)d_in[3];
    const int* batch_recover  = (const int*)d_in[5];
    const int* batch_label    = (const int*)d_in[7];
    const float* char_emb = (const float*)d_in[8];
    const float* conv_w   = (const float*)d_in[9];
    const float* conv_b   = (const float*)d_in[10];
    const float* word_emb = (const float*)d_in[11];
    const float* feat_emb = (const float*)d_in[12];
    const float* w_ih_f   = (const float*)d_in[13];
    const float* w_hh_f   = (const float*)d_in[14];
    const float* b_f      = (const float*)d_in[15];
    const float* w_ih_b   = (const float*)d_in[16];
    const float* w_hh_b   = (const float*)d_in[17];
    const float* b_b      = (const float*)d_in[18];
    const float* proj_w   = (const float*)d_in[19];
    const float* proj_b   = (const float*)d_in[20];
    const float* trans    = (const float*)d_in[21];

    char* ws = (char*)d_ws;
    float* pooled = (float*)(ws + OFF_POOL);
    float* x      = (float*)(ws + OFF_X);
    float* h_f    = (float*)(ws + OFF_HF);
    float* h_b    = (float*)(ws + OFF_HB);
    float* xs_f   = (float*)(ws + OFF_XSF);
    float* xs_b   = (float*)(ws + OFF_XSB);
    float* feats  = (float*)(ws + OFF_FEATS);
    _Float16* wh_f = (_Float16*)(ws + OFF_WPF);
    _Float16* wh_b = (_Float16*)(ws + OFF_WPB);
    float* lossb  = (float*)(ws + OFF_LOSSB);

    k_packh<<<1024, 256, 0, stream>>>(w_hh_f, wh_f);
    k_packh<<<1024, 256, 0, stream>>>(w_hh_b, wh_b);
    k_charcnn<<<BB * TT, 128, 0, stream>>>(batch_char, char_emb, conv_w, conv_b, pooled);
    k_concat<<<BB * TT, 128, 0, stream>>>(batch_word, batch_features, batch_recover,
                                          word_emb, feat_emb, pooled, x);
    k_gemm<<<dim3(G4 / BN, (BB * TT) / BM), 256, 0, stream>>>(x, w_ih_f, b_f, xs_f);
    k_gemm<<<dim3(G4 / BN, (BB * TT) / BM), 256, 0, stream>>>(x, w_ih_b, b_b, xs_b);
    k_lstm<<<64, 1024, 0, stream>>>(xs_f, xs_b, wh_f, wh_b, batch_wordlen, h_f, h_b);
    k_proj<<<BB * TT, 64, 0, stream>>>(h_f, h_b, proj_w, proj_b, feats);
    k_crf<<<BB, 64, 0, stream>>>(feats, trans, batch_wordlen, batch_label,
                                 lossb, (float*)d_out + 1);
    k_loss<<<1, 64, 0, stream>>>(lossb, (float*)d_out);
}

// Round 5
// 3050.778 us; speedup vs baseline: 2.2937x; 1.3360x over previous
//
#include <hip/hip_runtime.h>
#include <hip/hip_bf16.h>
#include <math.h>

#define BB 64
#define TT 256
#define LCH 16
#define DC 50
#define CHN 100
#define DW 300
#define DF 20
#define HID 256
#define G4 1024
#define INDIM 420
#define NTAG 52
#define TSTART 50
#define TSTOP 51

// ------------------- workspace layout (bytes) -------------------
static constexpr size_t OFF_POOL  = 0;                       // 6,553,600
static constexpr size_t OFF_X     = 6553600;                 // 27,525,120 -> end 34,078,720
static constexpr size_t OFF_HF    = 0;                       // 16,777,216 (overlaps pooled+x, dead by then)
static constexpr size_t OFF_HB    = 16777216;                // 16,777,216 -> 33,554,432
static constexpr size_t OFF_XSF   = 34078720;                // 67,108,864
static constexpr size_t OFF_XSB   = 101187584;               // 67,108,864 -> 168,296,448
static constexpr size_t OFF_FEATS = 168296448;               // 3,407,872  -> 171,704,320
static constexpr size_t OFF_WPF   = 171704320;               // 512 KB used (fp16, 262144 elems)
static constexpr size_t OFF_WPB   = 172752896;               // 512 KB used (fp16, 262144 elems)
static constexpr size_t OFF_LOSSB = 173801472;               // 256

typedef _Float16 v2h __attribute__((ext_vector_type(2)));
union UH2 { unsigned u; v2h h; };
__device__ __forceinline__ float fdot2u(unsigned a, unsigned b, float c) {
    UH2 x, y; x.u = a; y.u = b;
    return __builtin_amdgcn_fdot2(x.h, y.h, c, false);
}
__device__ __forceinline__ float dot8(uint4 w, uint4 h, float acc) {
    acc = fdot2u(w.x, h.x, acc);
    acc = fdot2u(w.y, h.y, acc);
    acc = fdot2u(w.z, h.z, acc);
    acc = fdot2u(w.w, h.w, acc);
    return acc;
}

__device__ __forceinline__ float sigm(float x) { return 1.0f / (1.0f + expf(-x)); }

// ---- pack W_hh (1024x256 f32, rows = gate*256+j) into fp16 lane-major layout:
//   wph[(((s*4+g)*8 + k8)*256 + j)*8 + r] = (f16) W[g*256+j][s*64 + k8*8 + r]
// total elements = 4*4*8*256*8 = 262144
__global__ void k_packh(const float* __restrict__ w, _Float16* __restrict__ wph) {
    int e = blockIdx.x * 256 + threadIdx.x;     // 0..262143 (grid must be 1024 blocks)
    if (e >= 262144) return;
    int r  = e & 7;
    int j  = (e >> 3) & 255;
    int k8 = (e >> 11) & 7;
    int g  = (e >> 14) & 3;
    int s  = (e >> 16) & 3;
    wph[e] = (_Float16)w[(g * 256 + j) * HID + (s * 64 + k8 * 8 + r)];
}

// ---- char CNN: one block (128 thr) per word; conv k=3 pad=1 over L=16, maxpool
__global__ __launch_bounds__(128) void k_charcnn(const int* __restrict__ bchar,
                                                 const float* __restrict__ cemb,
                                                 const float* __restrict__ cw,
                                                 const float* __restrict__ cb,
                                                 float* __restrict__ pooled) {
    __shared__ float ET[DC][20];   // transposed emb with halo cols 0 and 17 = 0
    __shared__ int ids[LCH];
    int w = blockIdx.x;
    int tid = threadIdx.x;
    if (tid < LCH) ids[tid] = bchar[w * LCH + tid];
    __syncthreads();
    for (int s = tid; s < DC * 18; s += 128) {
        int d = s / 18, l = s % 18;
        float v = 0.f;
        if (l >= 1 && l <= 16) v = cemb[ids[l - 1] * DC + d];
        ET[d][l] = v;
    }
    __syncthreads();
    if (tid < CHN) {
        float acc[16];
#pragma unroll
        for (int l = 0; l < 16; l++) acc[l] = 0.f;
        for (int d = 0; d < DC; d++) {
            float e[18];
            float4 t0 = *(const float4*)&ET[d][0];
            float4 t1 = *(const float4*)&ET[d][4];
            float4 t2 = *(const float4*)&ET[d][8];
            float4 t3 = *(const float4*)&ET[d][12];
            e[0]=t0.x; e[1]=t0.y; e[2]=t0.z; e[3]=t0.w;
            e[4]=t1.x; e[5]=t1.y; e[6]=t1.z; e[7]=t1.w;
            e[8]=t2.x; e[9]=t2.y; e[10]=t2.z; e[11]=t2.w;
            e[12]=t3.x; e[13]=t3.y; e[14]=t3.z; e[15]=t3.w;
            e[16]=ET[d][16]; e[17]=ET[d][17];
            float w0 = cw[(tid * DC + d) * 3 + 0];
            float w1 = cw[(tid * DC + d) * 3 + 1];
            float w2 = cw[(tid * DC + d) * 3 + 2];
#pragma unroll
            for (int l = 0; l < 16; l++)
                acc[l] += w0 * e[l] + w1 * e[l + 1] + w2 * e[l + 2];
        }
        float m = acc[0];
#pragma unroll
        for (int l = 1; l < 16; l++) m = fmaxf(m, acc[l]);
        pooled[w * CHN + tid] = m + cb[tid];
    }
}

// ---- assemble x[16384][420] = [word_emb | char_feats(recovered) | feat_emb]
__global__ __launch_bounds__(128) void k_concat(const int* __restrict__ word,
                                                const int* __restrict__ featsidx,
                                                const int* __restrict__ recover,
                                                const float* __restrict__ wemb,
                                                const float* __restrict__ femb,
                                                const float* __restrict__ pooled,
                                                float* __restrict__ x) {
    int w = blockIdx.x;
    int tid = threadIdx.x;
    int b = w >> 8;
    int wid = word[w];
    for (int c = tid; c < DW; c += 128) x[(size_t)w * INDIM + c] = wemb[(size_t)wid * DW + c];
    int rc = recover[w];
    if (tid < CHN) x[(size_t)w * INDIM + DW + tid] = pooled[rc * CHN + tid];
    if (tid < DF)  x[(size_t)w * INDIM + DW + CHN + tid] = femb[featsidx[b] * DF + tid];
}

// ---- fp32 GEMM: C[m][g] = sum_k A[m][k]*W[g][k] + bias[g];  M=16384 N=1024 K=420
#define BM 128
#define BN 64
#define BK 16
__global__ __launch_bounds__(256) void k_gemm(const float* __restrict__ A,
                                              const float* __restrict__ Wt,
                                              const float* __restrict__ bias,
                                              float* __restrict__ C) {
    __shared__ float As[BK][BM];
    __shared__ float Bs[BK][BN];
    int tid = threadIdx.x;
    int tx = tid & 15, ty = tid >> 4;
    int m0 = blockIdx.y * BM, n0 = blockIdx.x * BN;
    float acc[8][4];
#pragma unroll
    for (int i = 0; i < 8; i++)
#pragma unroll
        for (int jj = 0; jj < 4; jj++) acc[i][jj] = 0.f;
    int am = tid >> 1, ak = (tid & 1) * 8;
    int bn = tid >> 2, bk = (tid & 3) * 4;
    for (int k0 = 0; k0 < INDIM; k0 += BK) {
#pragma unroll
        for (int q = 0; q < 8; q++) {
            int k = k0 + ak + q;
            As[ak + q][am] = (k < INDIM) ? A[(size_t)(m0 + am) * INDIM + k] : 0.f;
        }
#pragma unroll
        for (int q = 0; q < 4; q++) {
            int k = k0 + bk + q;
            Bs[bk + q][bn] = (k < INDIM) ? Wt[(size_t)(n0 + bn) * INDIM + k] : 0.f;
        }
        __syncthreads();
#pragma unroll
        for (int kk = 0; kk < BK; kk++) {
            float4 a0 = *(const float4*)&As[kk][ty * 8];
            float4 a1 = *(const float4*)&As[kk][ty * 8 + 4];
            float4 b0 = *(const float4*)&Bs[kk][tx * 4];
            float ra[8] = {a0.x, a0.y, a0.z, a0.w, a1.x, a1.y, a1.z, a1.w};
            float rb[4] = {b0.x, b0.y, b0.z, b0.w};
#pragma unroll
            for (int i = 0; i < 8; i++)
#pragma unroll
                for (int jj = 0; jj < 4; jj++) acc[i][jj] += ra[i] * rb[jj];
        }
        __syncthreads();
    }
    float4 bv = *(const float4*)&bias[n0 + tx * 4];
#pragma unroll
    for (int i = 0; i < 8; i++) {
        float4 o;
        o.x = acc[i][0] + bv.x; o.y = acc[i][1] + bv.y;
        o.z = acc[i][2] + bv.z; o.w = acc[i][3] + bv.w;
        *(float4*)&C[(size_t)(m0 + ty * 8 + i) * G4 + n0 + tx * 4] = o;
    }
}

// ---- masked BiLSTM: one 1024-thread block per (batch, dir); 128 blocks.
// CU-resident weights: gates i,f,g in 96 VGPRs/thread; gate o in 128 KB LDS.
// Zero weight traffic from L2/HBM in the step loop.
// thread (j = tid&255, s = tid>>8) computes gate partials for unit j over
// k in [64s, 64s+64); epilogue threads (tid<128) each own 2 adjacent units.
__global__ __launch_bounds__(1024) void k_lstm(const float* __restrict__ xs_f,
                                               const float* __restrict__ xs_b,
                                               const _Float16* __restrict__ wh_f,
                                               const _Float16* __restrict__ wh_b,
                                               const int* __restrict__ wlen,
                                               float* __restrict__ h_f,
                                               float* __restrict__ h_b) {
    int b = blockIdx.x & 63, d = blockIdx.x >> 6;
    const float* xs = d ? xs_b : xs_f;
    const uint4* wp4 = (const uint4*)(d ? wh_b : wh_f);
    float* ho = d ? h_b : h_f;
    int len = wlen[b];
    __shared__ uint4 olds4[8192];                 // o-gate weights, 128 KB
    __shared__ unsigned __align__(16) hh[128];    // f16x2-packed h state (256 units)
    __shared__ float part[4][4][256];             // [s][gate][unit], 16 KB
    int tid = threadIdx.x;
    int j = tid & 255, s = tid >> 8;
    // ---- stage weights: gates 0..2 -> registers, gate 3 -> LDS ----
    uint4 wr0[8], wr1[8], wr2[8];
    {
        const uint4* wq0 = wp4 + (size_t)((s * 4 + 0) * 8) * 256 + j;
        const uint4* wq1 = wp4 + (size_t)((s * 4 + 1) * 8) * 256 + j;
        const uint4* wq2 = wp4 + (size_t)((s * 4 + 2) * 8) * 256 + j;
        const uint4* wq3 = wp4 + (size_t)((s * 4 + 3) * 8) * 256 + j;
#pragma unroll
        for (int k8 = 0; k8 < 8; k8++) {
            wr0[k8] = wq0[k8 * 256];
            wr1[k8] = wq1[k8 * 256];
            wr2[k8] = wq2[k8 * 256];
            olds4[k8 * 1024 + tid] = wq3[k8 * 256];
        }
    }
    if (tid < 128) hh[tid] = 0u;
    float c0 = 0.f, c1 = 0.f;                     // epilogue cell states (2 units)
    const uint4* hsh4 = (const uint4*)hh;
    __syncthreads();
    for (int ss = 0; ss < len; ++ss) {
        int t = d ? (len - 1 - ss) : ss;
        // prefetch x for this step (consumed after the barrier, in the epilogue)
        float2 xv0, xv1, xv2, xv3;
        if (tid < 128) {
            const float2* xr2 = (const float2*)(xs + (size_t)(b * TT + t) * G4);
            xv0 = xr2[0 * 128 + tid];
            xv1 = xr2[1 * 128 + tid];
            xv2 = xr2[2 * 128 + tid];
            xv3 = xr2[3 * 128 + tid];
        }
        float a0 = 0.f, a1 = 0.f, a2 = 0.f, a3 = 0.f;
#pragma unroll
        for (int k8 = 0; k8 < 8; k8++) {
            uint4 h4 = hsh4[s * 8 + k8];          // same-address broadcast within wave
            uint4 wo = olds4[k8 * 1024 + tid];    // conflict-free stride-16B
            a0 = dot8(wr0[k8], h4, a0);
            a1 = dot8(wr1[k8], h4, a1);
            a2 = dot8(wr2[k8], h4, a2);
            a3 = dot8(wo, h4, a3);
        }
        part[s][0][j] = a0;
        part[s][1][j] = a1;
        part[s][2][j] = a2;
        part[s][3][j] = a3;
        __syncthreads();
        if (tid < 128) {
            float sum[4][2];
#pragma unroll
            for (int g = 0; g < 4; g++) {
                float2 p0 = *(const float2*)&part[0][g][2 * tid];
                float2 p1 = *(const float2*)&part[1][g][2 * tid];
                float2 p2 = *(const float2*)&part[2][g][2 * tid];
                float2 p3 = *(const float2*)&part[3][g][2 * tid];
                sum[g][0] = p0.x + p1.x + p2.x + p3.x;
                sum[g][1] = p0.y + p1.y + p2.y + p3.y;
            }
            sum[0][0] += xv0.x; sum[0][1] += xv0.y;
            sum[1][0] += xv1.x; sum[1][1] += xv1.y;
            sum[2][0] += xv2.x; sum[2][1] += xv2.y;
            sum[3][0] += xv3.x; sum[3][1] += xv3.y;
            float i0 = sigm(sum[0][0]), f0 = sigm(sum[1][0]);
            float z0 = tanhf(sum[2][0]), o0 = sigm(sum[3][0]);
            c0 = f0 * c0 + i0 * z0;
            float hA = o0 * tanhf(c0);
            float i1 = sigm(sum[0][1]), f1 = sigm(sum[1][1]);
            float z1 = tanhf(sum[2][1]), o1 = sigm(sum[3][1]);
            c1 = f1 * c1 + i1 * z1;
            float hB = o1 * tanhf(c1);
            UH2 pk;
            pk.h[0] = (_Float16)hA;
            pk.h[1] = (_Float16)hB;
            hh[tid] = pk.u;
            float2 st; st.x = hA; st.y = hB;
            *(float2*)&ho[(size_t)(b * TT + t) * HID + 2 * tid] = st;
        }
        __syncthreads();
    }
}

// ---- projection: feats[w][52] = [hf|hb] . proj_w[j] + proj_b[j]
__global__ __launch_bounds__(64) void k_proj(const float* __restrict__ hf,
                                             const float* __restrict__ hb,
                                             const float* __restrict__ pw,
                                             const float* __restrict__ pb,
                                             float* __restrict__ feats) {
    __shared__ float hc[512];
    int w = blockIdx.x;
    int tid = threadIdx.x;
    {
        float4 v = *(const float4*)&hf[(size_t)w * HID + tid * 4];
        *(float4*)&hc[tid * 4] = v;
        float4 u = *(const float4*)&hb[(size_t)w * HID + tid * 4];
        *(float4*)&hc[256 + tid * 4] = u;
    }
    __syncthreads();
    if (tid < NTAG) {
        float s = pb[tid];
        for (int k = 0; k < 512; k += 4) {
            float4 h4 = *(const float4*)&hc[k];
            float4 w4 = *(const float4*)&pw[(size_t)tid * 512 + k];
            s += h4.x * w4.x + h4.y * w4.y + h4.z * w4.z + h4.w * w4.w;
        }
        feats[(size_t)w * NTAG + tid] = s;
    }
}

// ---- CRF: forward (Z), gold score, viterbi + backtrace. one block per batch
__global__ __launch_bounds__(64) void k_crf(const float* __restrict__ feats,
                                            const float* __restrict__ trans,
                                            const int* __restrict__ wlen,
                                            const int* __restrict__ blabel,
                                            float* __restrict__ lossb,
                                            float* __restrict__ outtags) {
    __shared__ float Tm[NTAG * NTAG];
    __shared__ float alpha[NTAG], valpha[NTAG], frow[NTAG], red[NTAG];
    __shared__ unsigned char bp[TT - 1][NTAG];
    int b = blockIdx.x;
    int j = threadIdx.x;
    for (int s = j; s < NTAG * NTAG; s += 64) Tm[s] = trans[s];
    __syncthreads();
    int len = wlen[b];
    const float* fb = feats + (size_t)b * TT * NTAG;
    if (j < NTAG) {
        float a = fb[j] + Tm[TSTART * NTAG + j];
        alpha[j] = a;
        valpha[j] = a;
    }
    __syncthreads();
    for (int t = 1; t < len; t++) {
        if (j < NTAG) frow[j] = fb[(size_t)t * NTAG + j];
        __syncthreads();
        float anew = 0.f, vnew = 0.f;
        int arg = 0;
        if (j < NTAG) {
            float m1 = -1e30f;
            for (int i = 0; i < NTAG; i++) m1 = fmaxf(m1, alpha[i] + Tm[i * NTAG + j]);
            float ssum = 0.f;
            for (int i = 0; i < NTAG; i++) ssum += expf(alpha[i] + Tm[i * NTAG + j] - m1);
            anew = m1 + logf(ssum) + frow[j];
            float vm = -1e30f;
            for (int i = 0; i < NTAG; i++) {
                float sv = valpha[i] + Tm[i * NTAG + j];
                if (sv > vm) { vm = sv; arg = i; }   // strict > keeps first max (jnp.argmax)
            }
            vnew = vm + frow[j];
        }
        __syncthreads();
        if (j < NTAG) {
            alpha[j] = anew;
            valpha[j] = vnew;
            bp[t - 1][j] = (unsigned char)arg;
        }
        __syncthreads();
    }
    // ---- Z + gold (thread 0) ----
    if (j < NTAG) red[j] = alpha[j] + Tm[j * NTAG + TSTOP];
    __syncthreads();
    float Zg = 0.f, goldv = 0.f;
    if (j == 0) {
        float m1 = red[0];
        for (int i = 1; i < NTAG; i++) m1 = fmaxf(m1, red[i]);
        float ssum = 0.f;
        for (int i = 0; i < NTAG; i++) ssum += expf(red[i] - m1);
        Zg = m1 + logf(ssum);
        const int* lab = blabel + b * TT;
        goldv = Tm[TSTART * NTAG + lab[0]] + fb[lab[0]];
        for (int t = 1; t < len; t++)
            goldv += Tm[lab[t - 1] * NTAG + lab[t]] + fb[(size_t)t * NTAG + lab[t]];
        goldv += Tm[lab[len - 1] * NTAG + TSTOP];
    }
    __syncthreads();
    // ---- viterbi terminal + backtrace ----
    if (j < NTAG) red[j] = valpha[j] + Tm[j * NTAG + TSTOP];
    __syncthreads();
    if (j == 0) {
        int best = 0;
        float vm = red[0];
        for (int i = 1; i < NTAG; i++)
            if (red[i] > vm) { vm = red[i]; best = i; }
        float* ot = outtags + (size_t)b * TT;
        int tag = best;
        ot[len - 1] = (float)tag;
        for (int t = len - 2; t >= 0; t--) {
            tag = bp[t][tag];
            ot[t] = (float)tag;
        }
        for (int t = len; t < TT; t++) ot[t] = 0.f;
        lossb[b] = Zg - goldv;
    }
}

// ---- deterministic final loss reduction
__global__ void k_loss(const float* __restrict__ lossb, float* __restrict__ out) {
    if (threadIdx.x == 0 && blockIdx.x == 0) {
        float s = 0.f;
        for (int i = 0; i < BB; i++) s += lossb[i];
        out[0] = s;
    }
}

extern "C" void kernel_launch(void* const* d_in, const int* in_sizes, int n_in,
                              void* d_out, int out_size, void* d_ws, size_t ws_size,
                              hipStream_t stream) {
    const int* batch_word     = (const int*)d_in[0];
    const int* batch_features = (const int*)d_in[1];
    const int* batch_wordlen  = (const int*)d_in[2];
    const int* batch_char     = (const int*)d_in[3];
    const int* batch_recover  = (const int*)d_in[5];
    const int* batch_label    = (const int*)d_in[7];
    const float* char_emb = (const float*)d_in[8];
    const float* conv_w   = (const float*)d_in[9];
    const float* conv_b   = (const float*)d_in[10];
    const float* word_emb = (const float*)d_in[11];
    const float* feat_emb = (const float*)d_in[12];
    const float* w_ih_f   = (const float*)d_in[13];
    const float* w_hh_f   = (const float*)d_in[14];
    const float* b_f      = (const float*)d_in[15];
    const float* w_ih_b   = (const float*)d_in[16];
    const float* w_hh_b   = (const float*)d_in[17];
    const float* b_b      = (const float*)d_in[18];
    const float* proj_w   = (const float*)d_in[19];
    const float* proj_b   = (const float*)d_in[20];
    const float* trans    = (const float*)d_in[21];

    char* ws = (char*)d_ws;
    float* pooled = (float*)(ws + OFF_POOL);
    float* x      = (float*)(ws + OFF_X);
    float* h_f    = (float*)(ws + OFF_HF);
    float* h_b    = (float*)(ws + OFF_HB);
    float* xs_f   = (float*)(ws + OFF_XSF);
    float* xs_b   = (float*)(ws + OFF_XSB);
    float* feats  = (float*)(ws + OFF_FEATS);
    _Float16* wh_f = (_Float16*)(ws + OFF_WPF);
    _Float16* wh_b = (_Float16*)(ws + OFF_WPB);
    float* lossb  = (float*)(ws + OFF_LOSSB);

    k_packh<<<1024, 256, 0, stream>>>(w_hh_f, wh_f);
    k_packh<<<1024, 256, 0, stream>>>(w_hh_b, wh_b);
    k_charcnn<<<BB * TT, 128, 0, stream>>>(batch_char, char_emb, conv_w, conv_b, pooled);
    k_concat<<<BB * TT, 128, 0, stream>>>(batch_word, batch_features, batch_recover,
                                          word_emb, feat_emb, pooled, x);
    k_gemm<<<dim3(G4 / BN, (BB * TT) / BM), 256, 0, stream>>>(x, w_ih_f, b_f, xs_f);
    k_gemm<<<dim3(G4 / BN, (BB * TT) / BM), 256, 0, stream>>>(x, w_ih_b, b_b, xs_b);
    k_lstm<<<128, 1024, 0, stream>>>(xs_f, xs_b, wh_f, wh_b, batch_wordlen, h_f, h_b);
    k_proj<<<BB * TT, 64, 0, stream>>>(h_f, h_b, proj_w, proj_b, feats);
    k_crf<<<BB, 64, 0, stream>>>(feats, trans, batch_wordlen, batch_label,
                                 lossb, (float*)d_out + 1);
    k_loss<<<1, 64, 0, stream>>>(lossb, (float*)d_out);
}

// Round 6
// 3035.217 us; speedup vs baseline: 2.3055x; 1.0051x over previous
//
#include <hip/hip_runtime.h>
#include <hip/hip_bf16.h>
#include <math.h>

#define BB 64
#define TT 256
#define LCH 16
#define DC 50
#define CHN 100
#define DW 300
#define DF 20
#define HID 256
#define G4 1024
#define INDIM 420
#define NTAG 52
#define TSTART 50
#define TSTOP 51

// ------------------- workspace layout (bytes) -------------------
static constexpr size_t OFF_POOL  = 0;                       // 6,553,600
static constexpr size_t OFF_X     = 6553600;                 // 27,525,120 -> end 34,078,720
static constexpr size_t OFF_HF    = 0;                       // 16,777,216 (overlaps pooled+x, dead by then)
static constexpr size_t OFF_HB    = 16777216;                // 16,777,216 -> 33,554,432
static constexpr size_t OFF_XSF   = 34078720;                // 67,108,864
static constexpr size_t OFF_XSB   = 101187584;               // 67,108,864 -> 168,296,448
static constexpr size_t OFF_FEATS = 168296448;               // 3,407,872  -> 171,704,320
static constexpr size_t OFF_WPF   = 171704320;               // 512 KB used (fp16, 262144 elems)
static constexpr size_t OFF_WPB   = 172752896;               // 512 KB used (fp16, 262144 elems)
static constexpr size_t OFF_LOSSB = 173801472;               // 256

typedef _Float16 v2h __attribute__((ext_vector_type(2)));
union UH2 { unsigned u; v2h h; };
__device__ __forceinline__ float fdot2u(unsigned a, unsigned b, float c) {
    UH2 x, y; x.u = a; y.u = b;
    return __builtin_amdgcn_fdot2(x.h, y.h, c, false);
}
__device__ __forceinline__ float dot8(uint4 w, uint4 h, float acc) {
    acc = fdot2u(w.x, h.x, acc);
    acc = fdot2u(w.y, h.y, acc);
    acc = fdot2u(w.z, h.z, acc);
    acc = fdot2u(w.w, h.w, acc);
    return acc;
}

__device__ __forceinline__ float sigm(float x) { return 1.0f / (1.0f + expf(-x)); }

// ---- pack W_hh (1024x256 f32, rows = gate*256+j) into fp16 lane-major layout:
//   wph[(((s*4+g)*8 + k8)*256 + j)*8 + r] = (f16) W[g*256+j][s*64 + k8*8 + r]
// total elements = 4*4*8*256*8 = 262144
__global__ void k_packh(const float* __restrict__ w, _Float16* __restrict__ wph) {
    int e = blockIdx.x * 256 + threadIdx.x;     // 0..262143 (grid must be 1024 blocks)
    if (e >= 262144) return;
    int r  = e & 7;
    int j  = (e >> 3) & 255;
    int k8 = (e >> 11) & 7;
    int g  = (e >> 14) & 3;
    int s  = (e >> 16) & 3;
    wph[e] = (_Float16)w[(g * 256 + j) * HID + (s * 64 + k8 * 8 + r)];
}

// ---- char CNN: one block (128 thr) per word; conv k=3 pad=1 over L=16, maxpool
__global__ __launch_bounds__(128) void k_charcnn(const int* __restrict__ bchar,
                                                 const float* __restrict__ cemb,
                                                 const float* __restrict__ cw,
                                                 const float* __restrict__ cb,
                                                 float* __restrict__ pooled) {
    __shared__ float ET[DC][20];   // transposed emb with halo cols 0 and 17 = 0
    __shared__ int ids[LCH];
    int w = blockIdx.x;
    int tid = threadIdx.x;
    if (tid < LCH) ids[tid] = bchar[w * LCH + tid];
    __syncthreads();
    for (int s = tid; s < DC * 18; s += 128) {
        int d = s / 18, l = s % 18;
        float v = 0.f;
        if (l >= 1 && l <= 16) v = cemb[ids[l - 1] * DC + d];
        ET[d][l] = v;
    }
    __syncthreads();
    if (tid < CHN) {
        float acc[16];
#pragma unroll
        for (int l = 0; l < 16; l++) acc[l] = 0.f;
        for (int d = 0; d < DC; d++) {
            float e[18];
            float4 t0 = *(const float4*)&ET[d][0];
            float4 t1 = *(const float4*)&ET[d][4];
            float4 t2 = *(const float4*)&ET[d][8];
            float4 t3 = *(const float4*)&ET[d][12];
            e[0]=t0.x; e[1]=t0.y; e[2]=t0.z; e[3]=t0.w;
            e[4]=t1.x; e[5]=t1.y; e[6]=t1.z; e[7]=t1.w;
            e[8]=t2.x; e[9]=t2.y; e[10]=t2.z; e[11]=t2.w;
            e[12]=t3.x; e[13]=t3.y; e[14]=t3.z; e[15]=t3.w;
            e[16]=ET[d][16]; e[17]=ET[d][17];
            float w0 = cw[(tid * DC + d) * 3 + 0];
            float w1 = cw[(tid * DC + d) * 3 + 1];
            float w2 = cw[(tid * DC + d) * 3 + 2];
#pragma unroll
            for (int l = 0; l < 16; l++)
                acc[l] += w0 * e[l] + w1 * e[l + 1] + w2 * e[l + 2];
        }
        float m = acc[0];
#pragma unroll
        for (int l = 1; l < 16; l++) m = fmaxf(m, acc[l]);
        pooled[w * CHN + tid] = m + cb[tid];
    }
}

// ---- assemble x[16384][420] = [word_emb | char_feats(recovered) | feat_emb]
__global__ __launch_bounds__(128) void k_concat(const int* __restrict__ word,
                                                const int* __restrict__ featsidx,
                                                const int* __restrict__ recover,
                                                const float* __restrict__ wemb,
                                                const float* __restrict__ femb,
                                                const float* __restrict__ pooled,
                                                float* __restrict__ x) {
    int w = blockIdx.x;
    int tid = threadIdx.x;
    int b = w >> 8;
    int wid = word[w];
    for (int c = tid; c < DW; c += 128) x[(size_t)w * INDIM + c] = wemb[(size_t)wid * DW + c];
    int rc = recover[w];
    if (tid < CHN) x[(size_t)w * INDIM + DW + tid] = pooled[rc * CHN + tid];
    if (tid < DF)  x[(size_t)w * INDIM + DW + CHN + tid] = femb[featsidx[b] * DF + tid];
}

// ---- fp32 GEMM: C[m][g] = sum_k A[m][k]*W[g][k] + bias[g];  M=16384 N=1024 K=420
#define BM 128
#define BN 64
#define BK 16
__global__ __launch_bounds__(256) void k_gemm(const float* __restrict__ A,
                                              const float* __restrict__ Wt,
                                              const float* __restrict__ bias,
                                              float* __restrict__ C) {
    __shared__ float As[BK][BM];
    __shared__ float Bs[BK][BN];
    int tid = threadIdx.x;
    int tx = tid & 15, ty = tid >> 4;
    int m0 = blockIdx.y * BM, n0 = blockIdx.x * BN;
    float acc[8][4];
#pragma unroll
    for (int i = 0; i < 8; i++)
#pragma unroll
        for (int jj = 0; jj < 4; jj++) acc[i][jj] = 0.f;
    int am = tid >> 1, ak = (tid & 1) * 8;
    int bn = tid >> 2, bk = (tid & 3) * 4;
    for (int k0 = 0; k0 < INDIM; k0 += BK) {
#pragma unroll
        for (int q = 0; q < 8; q++) {
            int k = k0 + ak + q;
            As[ak + q][am] = (k < INDIM) ? A[(size_t)(m0 + am) * INDIM + k] : 0.f;
        }
#pragma unroll
        for (int q = 0; q < 4; q++) {
            int k = k0 + bk + q;
            Bs[bk + q][bn] = (k < INDIM) ? Wt[(size_t)(n0 + bn) * INDIM + k] : 0.f;
        }
        __syncthreads();
#pragma unroll
        for (int kk = 0; kk < BK; kk++) {
            float4 a0 = *(const float4*)&As[kk][ty * 8];
            float4 a1 = *(const float4*)&As[kk][ty * 8 + 4];
            float4 b0 = *(const float4*)&Bs[kk][tx * 4];
            float ra[8] = {a0.x, a0.y, a0.z, a0.w, a1.x, a1.y, a1.z, a1.w};
            float rb[4] = {b0.x, b0.y, b0.z, b0.w};
#pragma unroll
            for (int i = 0; i < 8; i++)
#pragma unroll
                for (int jj = 0; jj < 4; jj++) acc[i][jj] += ra[i] * rb[jj];
        }
        __syncthreads();
    }
    float4 bv = *(const float4*)&bias[n0 + tx * 4];
#pragma unroll
    for (int i = 0; i < 8; i++) {
        float4 o;
        o.x = acc[i][0] + bv.x; o.y = acc[i][1] + bv.y;
        o.z = acc[i][2] + bv.z; o.w = acc[i][3] + bv.w;
        *(float4*)&C[(size_t)(m0 + ty * 8 + i) * G4 + n0 + tx * 4] = o;
    }
}

// ---- masked BiLSTM: one 1024-thread block per (batch, dir); 128 blocks.
// CU-resident weights: gates i,f,g in 96 VGPRs/thread; gate o in 128 KB LDS.
// __launch_bounds__(1024, 4): 16 waves/block = 4 waves/SIMD -> VGPR cap 128,
// enough to ACTUALLY hold the 96 weight regs (round-5 failure: default cap 64
// spilled them to scratch -> per-step L2 restream).
__global__ __launch_bounds__(1024, 4) void k_lstm(const float* __restrict__ xs_f,
                                               const float* __restrict__ xs_b,
                                               const _Float16* __restrict__ wh_f,
                                               const _Float16* __restrict__ wh_b,
                                               const int* __restrict__ wlen,
                                               float* __restrict__ h_f,
                                               float* __restrict__ h_b) {
    int b = blockIdx.x & 63, d = blockIdx.x >> 6;
    const float* xs = d ? xs_b : xs_f;
    const uint4* wp4 = (const uint4*)(d ? wh_b : wh_f);
    float* ho = d ? h_b : h_f;
    int len = wlen[b];
    __shared__ uint4 olds4[8192];                 // o-gate weights, 128 KB
    __shared__ unsigned __align__(16) hh[128];    // f16x2-packed h state (256 units)
    __shared__ float part[4][4][256];             // [s][gate][unit], 16 KB
    int tid = threadIdx.x;
    int j = tid & 255, s = tid >> 8;
    // ---- stage weights: gates 0..2 -> registers, gate 3 -> LDS ----
    uint4 wr0[8], wr1[8], wr2[8];
    {
        const uint4* wq0 = wp4 + (size_t)((s * 4 + 0) * 8) * 256 + j;
        const uint4* wq1 = wp4 + (size_t)((s * 4 + 1) * 8) * 256 + j;
        const uint4* wq2 = wp4 + (size_t)((s * 4 + 2) * 8) * 256 + j;
        const uint4* wq3 = wp4 + (size_t)((s * 4 + 3) * 8) * 256 + j;
#pragma unroll
        for (int k8 = 0; k8 < 8; k8++) {
            wr0[k8] = wq0[k8 * 256];
            wr1[k8] = wq1[k8 * 256];
            wr2[k8] = wq2[k8 * 256];
            olds4[k8 * 1024 + tid] = wq3[k8 * 256];
        }
    }
    if (tid < 128) hh[tid] = 0u;
    float c0 = 0.f, c1 = 0.f;                     // epilogue cell states (2 units)
    const uint4* hsh4 = (const uint4*)hh;
    __syncthreads();
    for (int ss = 0; ss < len; ++ss) {
        int t = d ? (len - 1 - ss) : ss;
        // prefetch x for this step (consumed after the barrier, in the epilogue)
        float2 xv0, xv1, xv2, xv3;
        if (tid < 128) {
            const float2* xr2 = (const float2*)(xs + (size_t)(b * TT + t) * G4);
            xv0 = xr2[0 * 128 + tid];
            xv1 = xr2[1 * 128 + tid];
            xv2 = xr2[2 * 128 + tid];
            xv3 = xr2[3 * 128 + tid];
        }
        float a0 = 0.f, a1 = 0.f, a2 = 0.f, a3 = 0.f;
#pragma unroll
        for (int k8 = 0; k8 < 8; k8++) {
            uint4 h4 = hsh4[s * 8 + k8];          // same-address broadcast within wave
            uint4 wo = olds4[k8 * 1024 + tid];    // conflict-free stride-16B
            a0 = dot8(wr0[k8], h4, a0);
            a1 = dot8(wr1[k8], h4, a1);
            a2 = dot8(wr2[k8], h4, a2);
            a3 = dot8(wo, h4, a3);
        }
        part[s][0][j] = a0;
        part[s][1][j] = a1;
        part[s][2][j] = a2;
        part[s][3][j] = a3;
        __syncthreads();
        if (tid < 128) {
            float sum[4][2];
#pragma unroll
            for (int g = 0; g < 4; g++) {
                float2 p0 = *(const float2*)&part[0][g][2 * tid];
                float2 p1 = *(const float2*)&part[1][g][2 * tid];
                float2 p2 = *(const float2*)&part[2][g][2 * tid];
                float2 p3 = *(const float2*)&part[3][g][2 * tid];
                sum[g][0] = p0.x + p1.x + p2.x + p3.x;
                sum[g][1] = p0.y + p1.y + p2.y + p3.y;
            }
            sum[0][0] += xv0.x; sum[0][1] += xv0.y;
            sum[1][0] += xv1.x; sum[1][1] += xv1.y;
            sum[2][0] += xv2.x; sum[2][1] += xv2.y;
            sum[3][0] += xv3.x; sum[3][1] += xv3.y;
            float i0 = sigm(sum[0][0]), f0 = sigm(sum[1][0]);
            float z0 = tanhf(sum[2][0]), o0 = sigm(sum[3][0]);
            c0 = f0 * c0 + i0 * z0;
            float hA = o0 * tanhf(c0);
            float i1 = sigm(sum[0][1]), f1 = sigm(sum[1][1]);
            float z1 = tanhf(sum[2][1]), o1 = sigm(sum[3][1]);
            c1 = f1 * c1 + i1 * z1;
            float hB = o1 * tanhf(c1);
            UH2 pk;
            pk.h[0] = (_Float16)hA;
            pk.h[1] = (_Float16)hB;
            hh[tid] = pk.u;
            float2 st; st.x = hA; st.y = hB;
            *(float2*)&ho[(size_t)(b * TT + t) * HID + 2 * tid] = st;
        }
        __syncthreads();
    }
}

// ---- projection: feats[w][52] = [hf|hb] . proj_w[j] + proj_b[j]
__global__ __launch_bounds__(64) void k_proj(const float* __restrict__ hf,
                                             const float* __restrict__ hb,
                                             const float* __restrict__ pw,
                                             const float* __restrict__ pb,
                                             float* __restrict__ feats) {
    __shared__ float hc[512];
    int w = blockIdx.x;
    int tid = threadIdx.x;
    {
        float4 v = *(const float4*)&hf[(size_t)w * HID + tid * 4];
        *(float4*)&hc[tid * 4] = v;
        float4 u = *(const float4*)&hb[(size_t)w * HID + tid * 4];
        *(float4*)&hc[256 + tid * 4] = u;
    }
    __syncthreads();
    if (tid < NTAG) {
        float s = pb[tid];
        for (int k = 0; k < 512; k += 4) {
            float4 h4 = *(const float4*)&hc[k];
            float4 w4 = *(const float4*)&pw[(size_t)tid * 512 + k];
            s += h4.x * w4.x + h4.y * w4.y + h4.z * w4.z + h4.w * w4.w;
        }
        feats[(size_t)w * NTAG + tid] = s;
    }
}

// ---- CRF: forward (Z), gold score, viterbi + backtrace. one block per batch
__global__ __launch_bounds__(64) void k_crf(const float* __restrict__ feats,
                                            const float* __restrict__ trans,
                                            const int* __restrict__ wlen,
                                            const int* __restrict__ blabel,
                                            float* __restrict__ lossb,
                                            float* __restrict__ outtags) {
    __shared__ float Tm[NTAG * NTAG];
    __shared__ float alpha[NTAG], valpha[NTAG], frow[NTAG], red[NTAG];
    __shared__ unsigned char bp[TT - 1][NTAG];
    int b = blockIdx.x;
    int j = threadIdx.x;
    for (int s = j; s < NTAG * NTAG; s += 64) Tm[s] = trans[s];
    __syncthreads();
    int len = wlen[b];
    const float* fb = feats + (size_t)b * TT * NTAG;
    if (j < NTAG) {
        float a = fb[j] + Tm[TSTART * NTAG + j];
        alpha[j] = a;
        valpha[j] = a;
    }
    __syncthreads();
    for (int t = 1; t < len; t++) {
        if (j < NTAG) frow[j] = fb[(size_t)t * NTAG + j];
        __syncthreads();
        float anew = 0.f, vnew = 0.f;
        int arg = 0;
        if (j < NTAG) {
            float m1 = -1e30f;
            for (int i = 0; i < NTAG; i++) m1 = fmaxf(m1, alpha[i] + Tm[i * NTAG + j]);
            float ssum = 0.f;
            for (int i = 0; i < NTAG; i++) ssum += expf(alpha[i] + Tm[i * NTAG + j] - m1);
            anew = m1 + logf(ssum) + frow[j];
            float vm = -1e30f;
            for (int i = 0; i < NTAG; i++) {
                float sv = valpha[i] + Tm[i * NTAG + j];
                if (sv > vm) { vm = sv; arg = i; }   // strict > keeps first max (jnp.argmax)
            }
            vnew = vm + frow[j];
        }
        __syncthreads();
        if (j < NTAG) {
            alpha[j] = anew;
            valpha[j] = vnew;
            bp[t - 1][j] = (unsigned char)arg;
        }
        __syncthreads();
    }
    // ---- Z + gold (thread 0) ----
    if (j < NTAG) red[j] = alpha[j] + Tm[j * NTAG + TSTOP];
    __syncthreads();
    float Zg = 0.f, goldv = 0.f;
    if (j == 0) {
        float m1 = red[0];
        for (int i = 1; i < NTAG; i++) m1 = fmaxf(m1, red[i]);
        float ssum = 0.f;
        for (int i = 0; i < NTAG; i++) ssum += expf(red[i] - m1);
        Zg = m1 + logf(ssum);
        const int* lab = blabel + b * TT;
        goldv = Tm[TSTART * NTAG + lab[0]] + fb[lab[0]];
        for (int t = 1; t < len; t++)
            goldv += Tm[lab[t - 1] * NTAG + lab[t]] + fb[(size_t)t * NTAG + lab[t]];
        goldv += Tm[lab[len - 1] * NTAG + TSTOP];
    }
    __syncthreads();
    // ---- viterbi terminal + backtrace ----
    if (j < NTAG) red[j] = valpha[j] + Tm[j * NTAG + TSTOP];
    __syncthreads();
    if (j == 0) {
        int best = 0;
        float vm = red[0];
        for (int i = 1; i < NTAG; i++)
            if (red[i] > vm) { vm = red[i]; best = i; }
        float* ot = outtags + (size_t)b * TT;
        int tag = best;
        ot[len - 1] = (float)tag;
        for (int t = len - 2; t >= 0; t--) {
            tag = bp[t][tag];
            ot[t] = (float)tag;
        }
        for (int t = len; t < TT; t++) ot[t] = 0.f;
        lossb[b] = Zg - goldv;
    }
}

// ---- deterministic final loss reduction
__global__ void k_loss(const float* __restrict__ lossb, float* __restrict__ out) {
    if (threadIdx.x == 0 && blockIdx.x == 0) {
        float s = 0.f;
        for (int i = 0; i < BB; i++) s += lossb[i];
        out[0] = s;
    }
}

extern "C" void kernel_launch(void* const* d_in, const int* in_sizes, int n_in,
                              void* d_out, int out_size, void* d_ws, size_t ws_size,
                              hipStream_t stream) {
    const int* batch_word     = (const int*)d_in[0];
    const int* batch_features = (const int*)d_in[1];
    const int* batch_wordlen  = (const int*)d_in[2];
    const int* batch_char     = (const int*)d_in[3];
    const int* batch_recover  = (const int*)d_in[5];
    const int* batch_label    = (const int*)d_in[7];
    const float* char_emb = (const float*)d_in[8];
    const float* conv_w   = (const float*)d_in[9];
    const float* conv_b   = (const float*)d_in[10];
    const float* word_emb = (const float*)d_in[11];
    const float* feat_emb = (const float*)d_in[12];
    const float* w_ih_f   = (const float*)d_in[13];
    const float* w_hh_f   = (const float*)d_in[14];
    const float* b_f      = (const float*)d_in[15];
    const float* w_ih_b   = (const float*)d_in[16];
    const float* w_hh_b   = (const float*)d_in[17];
    const float* b_b      = (const float*)d_in[18];
    const float* proj_w   = (const float*)d_in[19];
    const float* proj_b   = (const float*)d_in[20];
    const float* trans    = (const float*)d_in[21];

    char* ws = (char*)d_ws;
    float* pooled = (float*)(ws + OFF_POOL);
    float* x      = (float*)(ws + OFF_X);
    float* h_f    = (float*)(ws + OFF_HF);
    float* h_b    = (float*)(ws + OFF_HB);
    float* xs_f   = (float*)(ws + OFF_XSF);
    float* xs_b   = (float*)(ws + OFF_XSB);
    float* feats  = (float*)(ws + OFF_FEATS);
    _Float16* wh_f = (_Float16*)(ws + OFF_WPF);
    _Float16* wh_b = (_Float16*)(ws + OFF_WPB);
    float* lossb  = (float*)(ws + OFF_LOSSB);

    k_packh<<<1024, 256, 0, stream>>>(w_hh_f, wh_f);
    k_packh<<<1024, 256, 0, stream>>>(w_hh_b, wh_b);
    k_charcnn<<<BB * TT, 128, 0, stream>>>(batch_char, char_emb, conv_w, conv_b, pooled);
    k_concat<<<BB * TT, 128, 0, stream>>>(batch_word, batch_features, batch_recover,
                                          word_emb, feat_emb, pooled, x);
    k_gemm<<<dim3(G4 / BN, (BB * TT) / BM), 256, 0, stream>>>(x, w_ih_f, b_f, xs_f);
    k_gemm<<<dim3(G4 / BN, (BB * TT) / BM), 256, 0, stream>>>(x, w_ih_b, b_b, xs_b);
    k_lstm<<<128, 1024, 0, stream>>>(xs_f, xs_b, wh_f, wh_b, batch_wordlen, h_f, h_b);
    k_proj<<<BB * TT, 64, 0, stream>>>(h_f, h_b, proj_w, proj_b, feats);
    k_crf<<<BB, 64, 0, stream>>>(feats, trans, batch_wordlen, batch_label,
                                 lossb, (float*)d_out + 1);
    k_loss<<<1, 64, 0, stream>>>(lossb, (float*)d_out);
}